// Round 10
// baseline (212.909 us; speedup 1.0000x reference)
//
#include <hip/hip_runtime.h>

// B=64, N=2048, DIM_IN=DIM_OUT=64, CHEB_K=3, EMBED_DIM=10
#define NN 2048
#define BB 64
#define CC 64
#define ED 10
#define KK 3
#define JJ (BB * CC)   // 4096

typedef unsigned short ushort_t;
typedef __attribute__((ext_vector_type(8))) short short8;   // 8 bf16 = 4 VGPRs
typedef __attribute__((ext_vector_type(4))) float f32x4;

typedef const __attribute__((address_space(1))) unsigned* gptr_t;
typedef __attribute__((address_space(3))) unsigned* lptr_t;
typedef __attribute__((address_space(3))) ushort_t* lsptr_t;
typedef const __attribute__((address_space(3))) short8* ls8_t;

static __device__ __forceinline__ ushort_t f2bf(float f) {
    union { float f; unsigned u; } x{f};
    unsigned r = x.u + 0x7FFF + ((x.u >> 16) & 1);  // RTN-even
    return (ushort_t)(r >> 16);
}
static __device__ __forceinline__ float bf2f(ushort_t h) {
    union { unsigned u; float f; } x;
    x.u = ((unsigned)h) << 16;
    return x.f;
}

// ---------------------------------------------------------------------------
// Kernel 1 (merged prep): round-7 version (float2 E-gather), verified.
// ---------------------------------------------------------------------------
__global__ __launch_bounds__(256) void prep_kernel(const float* __restrict__ E,
                                                   const float* __restrict__ x,
                                                   const float* __restrict__ Wp,
                                                   ushort_t* __restrict__ Ab,
                                                   ushort_t* __restrict__ xT,
                                                   ushort_t* __restrict__ xN,
                                                   ushort_t* __restrict__ WpT) {
    const int bid = blockIdx.x;
    const int tid = threadIdx.x;

    __shared__ float tb[64][68];
    __shared__ float red[8];

    if (bid < NN) {
        const int n = bid;
        float en[ED];
#pragma unroll
        for (int d = 0; d < ED; ++d) en[d] = E[n * ED + d];

        float sv[NN / 256];
        float lmax = 0.0f;
#pragma unroll
        for (int j = 0; j < NN / 256; ++j) {
            const int m = tid + j * 256;
            const float2* Em2 = (const float2*)(E + m * ED);  // 8-B aligned
            float dot = 0.0f;
#pragma unroll
            for (int d2 = 0; d2 < ED / 2; ++d2) {
                const float2 v = Em2[d2];
                dot += en[2 * d2] * v.x + en[2 * d2 + 1] * v.y;
            }
            float s = fmaxf(dot, 0.0f);
            sv[j] = s;
            lmax = fmaxf(lmax, s);
        }
#pragma unroll
        for (int off = 32; off > 0; off >>= 1) lmax = fmaxf(lmax, __shfl_down(lmax, off, 64));
        if ((tid & 63) == 0) red[tid >> 6] = lmax;
        __syncthreads();
        const float bmax = fmaxf(fmaxf(red[0], red[1]), fmaxf(red[2], red[3]));

        float lsum = 0.0f;
#pragma unroll
        for (int j = 0; j < NN / 256; ++j) {
            sv[j] = __expf(sv[j] - bmax);
            lsum += sv[j];
        }
#pragma unroll
        for (int off = 32; off > 0; off >>= 1) lsum += __shfl_down(lsum, off, 64);
        if ((tid & 63) == 0) red[4 + (tid >> 6)] = lsum;
        __syncthreads();
        const float inv = 1.0f / (red[4] + red[5] + red[6] + red[7]);

#pragma unroll
        for (int j = 0; j < NN / 256; ++j) {
            Ab[(size_t)n * NN + tid + j * 256] = f2bf(sv[j] * inv);
        }
    } else if (bid < 2 * NN) {
        const int t = bid - NN;
        const int n0 = (t & 31) * 64;
        const int b = t >> 5;

#pragma unroll
        for (int l = 0; l < 4; ++l) {
            const int idx = tid + l * 256;
            const int nn = idx >> 4;
            const int c4 = (idx & 15) << 2;
            const float4 v = *(const float4*)(x + ((size_t)b * NN + n0 + nn) * CC + c4);
            tb[c4 + 0][nn] = v.x;
            tb[c4 + 1][nn] = v.y;
            tb[c4 + 2][nn] = v.z;
            tb[c4 + 3][nn] = v.w;
        }
        __syncthreads();

#pragma unroll
        for (int l = 0; l < 2; ++l) {
            const int idx = tid + l * 256;
            const int c = idx >> 3;
            const int ch = (idx & 7) << 3;
            ushort_t pack[8];
#pragma unroll
            for (int e = 0; e < 8; ++e) pack[e] = f2bf(tb[c][ch + e]);
            *(float4*)(xT + (size_t)(b * 64 + c) * NN + n0 + ch) = *(float4*)pack;
        }
#pragma unroll
        for (int l = 0; l < 2; ++l) {
            const int idx = tid + l * 256;
            const int nn = idx >> 3;
            const int cg = (idx & 7) << 3;
            ushort_t pack[8];
#pragma unroll
            for (int e = 0; e < 8; ++e) pack[e] = f2bf(tb[cg + e][nn]);
            *(float4*)(xN + (size_t)(n0 + nn) * JJ + b * 64 + cg) = *(float4*)pack;
        }
    } else {
        const int dk = bid - 2 * NN;
        const float* src = Wp + (size_t)dk * CC * CC;

#pragma unroll
        for (int l = 0; l < 4; ++l) {
            const int idx = tid + l * 256;
            const int i = idx >> 4;
            const int o4 = (idx & 15) << 2;
            const float4 v = *(const float4*)(src + i * CC + o4);
            tb[o4 + 0][i] = v.x;
            tb[o4 + 1][i] = v.y;
            tb[o4 + 2][i] = v.z;
            tb[o4 + 3][i] = v.w;
        }
        __syncthreads();

#pragma unroll
        for (int l = 0; l < 2; ++l) {
            const int idx = tid + l * 256;
            const int o = idx >> 3;
            const int ic = (idx & 7) << 3;
            ushort_t pack[8];
#pragma unroll
            for (int e = 0; e < 8; ++e) pack[e] = f2bf(tb[o][ic + e]);
            *(float4*)(WpT + (size_t)dk * CC * CC + o * CC + ic) = *(float4*)pack;
        }
    }
}

// ---------------------------------------------------------------------------
// Kernel 2: rolled NT-GEMM — EXACT round-6 structure (best measured: 42.0 us,
// 819 TF). 128x256 tile, 8 waves of 64x64 (512 thr), BK=64, triple-buffered
// LDS (144 KB), 1 barrier/tile, counted vmcnt(6), deferred 2nd MFMA cluster.
// Round-10 change: MODE 1 writes RAW acc (A@y1) node-major — the 2*v-x fold
// moved to out_kernel (removes 64 scalar strided Zn gathers per thread).
// ---------------------------------------------------------------------------
#define STAGE_A(bp, kt) do {                                                                \
    __builtin_amdgcn_global_load_lds(                                                       \
        (gptr_t)(srcA + (size_t)(kt) * 64),                                                 \
        (lptr_t)&(bp)[dstoff], 16, 0, 0);                                                   \
    __builtin_amdgcn_global_load_lds(                                                       \
        (gptr_t)(srcA + (size_t)64 * NN + (size_t)(kt) * 64),                               \
        (lptr_t)&(bp)[4096 + dstoff], 16, 0, 0);                                            \
} while (0)

#define STAGE_B(bp, h, kt) do {                                                             \
    __builtin_amdgcn_global_load_lds(                                                       \
        (gptr_t)(srcB + (size_t)((h) * 2) * 64 * NN + (size_t)(kt) * 64),                   \
        (lptr_t)&(bp)[8192 + (h) * 8192 + dstoff], 16, 0, 0);                               \
    __builtin_amdgcn_global_load_lds(                                                       \
        (gptr_t)(srcB + (size_t)((h) * 2 + 1) * 64 * NN + (size_t)(kt) * 64),               \
        (lptr_t)&(bp)[8192 + (h) * 8192 + 4096 + dstoff], 16, 0, 0);                        \
} while (0)

#define LDA_ALL(bp) do {                                                                    \
    _Pragma("unroll") for (int mi_ = 0; mi_ < 4; ++mi_)                                     \
    _Pragma("unroll") for (int ks_ = 0; ks_ < 2; ++ks_)                                     \
        a[mi_][ks_] = *(ls8_t)&(bp)[(aRG + mi_) * 1024 + ks_ * 512 + rdofs];                \
} while (0)

#define LDB_H(bp, h) do {                                                                   \
    _Pragma("unroll") for (int nn_ = 0; nn_ < 2; ++nn_)                                     \
    _Pragma("unroll") for (int ks_ = 0; ks_ < 2; ++ks_)                                     \
        b[(h) * 2 + nn_][ks_] =                                                             \
            *(ls8_t)&(bp)[8192 + (bRG + (h) * 2 + nn_) * 1024 + ks_ * 512 + rdofs];         \
} while (0)

// cluster c covers ni = 2c..2c+1: 4 mi x 2 ni x 2 ks = 16 MFMAs
#define MFMA_C(c) do {                                                                      \
    __builtin_amdgcn_s_setprio(1);                                                          \
    _Pragma("unroll") for (int mi_ = 0; mi_ < 4; ++mi_)                                     \
    _Pragma("unroll") for (int nn_ = 0; nn_ < 2; ++nn_) {                                   \
        acc[mi_][(c) * 2 + nn_] = __builtin_amdgcn_mfma_f32_16x16x32_bf16(                  \
            a[mi_][0], b[(c) * 2 + nn_][0], acc[mi_][(c) * 2 + nn_], 0, 0, 0);              \
        acc[mi_][(c) * 2 + nn_] = __builtin_amdgcn_mfma_f32_16x16x32_bf16(                  \
            a[mi_][1], b[(c) * 2 + nn_][1], acc[mi_][(c) * 2 + nn_], 0, 0, 0);              \
    }                                                                                       \
    __builtin_amdgcn_s_setprio(0);                                                          \
} while (0)

template <int MODE>
__global__ __launch_bounds__(512, 2) void gemm_roll(const ushort_t* __restrict__ A,
                                                    const ushort_t* __restrict__ Bt,
                                                    ushort_t* __restrict__ Ct,
                                                    ushort_t* __restrict__ Cn) {
    // bijective XCD swizzle (256 % 8 == 0)
    int bid = blockIdx.x;
    bid = (bid & 7) * 32 + (bid >> 3);
    const int bx = bid & 15;        // j-tile (BN=256)
    const int by = bid >> 4;        // m-tile (BM=128)
    const int j0 = bx * 256;
    const int m0 = by * 128;

    const int tid = threadIdx.x;
    const int w = tid >> 6;
    const int lane = tid & 63;
    const int l16 = lane & 15;
    const int quad = lane >> 4;
    const int wm = (w >> 2) * 64;   // wave rows [wm, wm+64)
    const int wn = (w & 3) * 64;    // wave cols [wn, wn+64)
    const int aRG = (w >> 2) * 4;   // A subtile base (8 subtiles of 16 rows)
    const int bRG = (w & 3) * 4;    // B subtile base (16 subtiles)
    // swizzled ds_read offset (ushorts): row l16, k-chunk quad, st_16x32 XOR
    const int rdofs = l16 * 32 + ((quad * 8) ^ ((l16 & 8) * 2));

    // staging: linear LDS dest (tid*16B); inverse-swizzled SOURCE
    const int r16s = lane >> 2;
    const int cx = (lane & 3) ^ ((r16s >> 3) << 1);
    const int rowbase = (w >> 1) * 16 + r16s;         // row within 64-row unit
    const int kofs = (w & 1) * 32 + cx * 8;
    const ushort_t* srcA = A + (size_t)(m0 + rowbase) * NN + kofs;
    const ushort_t* srcB = Bt + (size_t)(j0 + rowbase) * NN + kofs;
    const int dstoff = tid * 8;

    __shared__ ushort_t lds[3][24576];  // 3 x (A 16KB | B 32KB) = 144 KB

    lsptr_t p0 = (lsptr_t)&lds[0][0];   // buf(t)
    lsptr_t p1 = (lsptr_t)&lds[1][0];   // buf(t+1)
    lsptr_t p2 = (lsptr_t)&lds[2][0];   // buf(t+2) = stage target

    f32x4 acc[4][4];
#pragma unroll
    for (int mi = 0; mi < 4; ++mi)
#pragma unroll
        for (int ni = 0; ni < 4; ++ni) acc[mi][ni] = (f32x4){0.f, 0.f, 0.f, 0.f};

    short8 a[4][2], b[4][2];

    // Prologue: stage t0 (oldest) then t1. Loop-top vmcnt(6) drains t0.
    STAGE_A(p0, 0); STAGE_B(p0, 0, 0); STAGE_B(p0, 1, 0);
    STAGE_A(p1, 1); STAGE_B(p1, 0, 1); STAGE_B(p1, 1, 1);

#pragma unroll 1
    for (int t = 0; t < 32; ++t) {
        // deferred cluster of tile t-1 (old a, b[2..3]) covers drain + reads
        if (t) MFMA_C(1);
        if (t < 31) { asm volatile("s_waitcnt vmcnt(6)" ::: "memory"); }
        else        { asm volatile("s_waitcnt vmcnt(0)" ::: "memory"); }
        __builtin_amdgcn_sched_barrier(0);
        __builtin_amdgcn_s_barrier();          // buf(t) collectively landed

        LDA_ALL(p0); LDB_H(p0, 0);             // 12 ds_reads
        const bool stg = (t < 30);
        if (stg) { STAGE_A(p2, t + 2); STAGE_B(p2, 0, t + 2); }
        asm volatile("s_waitcnt lgkmcnt(0)" ::: "memory");
        __builtin_amdgcn_sched_barrier(0);
        MFMA_C(0);                              // 16 MFMAs cover:
        LDB_H(p0, 1);                           // 4 tail reads (b[2..3])
        if (stg) STAGE_B(p2, 1, t + 2);
        __builtin_amdgcn_sched_barrier(0);

        lsptr_t tp = p0; p0 = p1; p1 = p2; p2 = tp;  // rotate buffers
    }
    MFMA_C(1);  // tile 31's second cluster

    // Epilogue: C/D col j = l16, row m = quad*4 + r.
#pragma unroll
    for (int mi = 0; mi < 4; ++mi) {
#pragma unroll
        for (int ji = 0; ji < 4; ++ji) {
            const int j = j0 + wn + ji * 16 + l16;
            const int mb = m0 + wm + mi * 16 + quad * 4;
            ushort_t o[4];
#pragma unroll
            for (int r = 0; r < 4; ++r) o[r] = f2bf(acc[mi][ji][r]);
            if (MODE == 0) {
                *(unsigned long long*)(Ct + (size_t)j * NN + mb) = *(unsigned long long*)o;
            }
#pragma unroll
            for (int r = 0; r < 4; ++r) Cn[(size_t)(mb + r) * JJ + j] = o[r];
        }
    }
}

#undef STAGE_A
#undef STAGE_B
#undef LDA_ALL
#undef LDB_H
#undef MFMA_C

// ---------------------------------------------------------------------------
// Kernel 3: MFMA epilogue — TWO nodes per block (512 thr: waves 0-3 -> n0,
// waves 4-7 -> n1). Both halves stream the SAME 245 KB WpT concurrently ->
// L2 WpT traffic halves (502 -> 251 MB). The y2 fold (2*y2raw - x) moved
// here from gemm<1>: staging reads xN/y1N/y2raw at the same index.
// LDS: 2 x (25.6 + 25.6) KB = 103 KB -> 1 block/CU, 8 waves.
// ---------------------------------------------------------------------------
#define XLD 200  // LDS row stride (bf16): 400 B -> 2-way bank alias (free)
__global__ __launch_bounds__(512) void out_kernel(const float* __restrict__ E,
                                                  const ushort_t* __restrict__ WpT,
                                                  const float* __restrict__ bp,
                                                  const ushort_t* __restrict__ xN,
                                                  const ushort_t* __restrict__ y1N,
                                                  const ushort_t* __restrict__ y2r,
                                                  float* __restrict__ out) {
    const int tid = threadIdx.x;
    const int half = tid >> 8;            // 0 or 1
    const int t8 = tid & 255;
    const int n = blockIdx.x * 2 + half;

    __shared__ ushort_t xg[2][BB * XLD];  // 2 x 25.6 KB
    __shared__ ushort_t Wt[2][CC * XLD];  // 2 x 25.6 KB
    __shared__ float en_s[2][ED];
    __shared__ float bias_s[2][CC];

    if (t8 < ED) en_s[half][t8] = E[n * ED + t8];
    __syncthreads();

    float en[ED];
#pragma unroll
    for (int d = 0; d < ED; ++d) en[d] = en_s[half][d];

    if (t8 < CC) {
        float bsum = 0.0f;
#pragma unroll
        for (int d = 0; d < ED; ++d) bsum += en[d] * bp[d * CC + t8];
        bias_s[half][t8] = bsum;
    }

    // stage X rows: xN -> k0, y1N -> k1, (2*y2raw - x) -> k2 (same idx).
    {
        const float4* sx = (const float4*)(xN + (size_t)n * JJ);
        const float4* s1 = (const float4*)(y1N + (size_t)n * JJ);
        const float4* s2 = (const float4*)(y2r + (size_t)n * JJ);
        for (int idx = t8; idx < JJ / 8; idx += 256) {
            const float4 xv = sx[idx];
            const float4 v1 = s1[idx];
            const float4 v2 = s2[idx];
            const int row = idx >> 3;
            const int col = (idx & 7) << 3;
            *(float4*)&xg[half][row * XLD + col] = xv;
            *(float4*)&xg[half][row * XLD + 64 + col] = v1;
            ushort_t pk[8];
            const ushort_t* px = (const ushort_t*)&xv;
            const ushort_t* p2 = (const ushort_t*)&v2;
#pragma unroll
            for (int e = 0; e < 8; ++e)
                pk[e] = f2bf(2.0f * bf2f(p2[e]) - bf2f(px[e]));
            *(float4*)&xg[half][row * XLD + 128 + col] = *(float4*)pk;
        }
    }

    // synthesize Wt[o][ki] bf16: 1536 chunks of 8, fp32 accumulate over d
    for (int t = t8; t < CC * 24; t += 256) {
        const int o = t / 24;
        const int kc = t % 24;
        const int k = kc >> 3;
        const int ic = (kc & 7) << 3;
        float s[8];
#pragma unroll
        for (int e = 0; e < 8; ++e) s[e] = 0.0f;
#pragma unroll
        for (int d = 0; d < ED; ++d) {
            const float4 wv4 = *(const float4*)(WpT + ((size_t)(d * KK + k) * CC + o) * CC + ic);
            const ushort_t* wp = (const ushort_t*)&wv4;
#pragma unroll
            for (int e = 0; e < 8; ++e) s[e] += en[d] * bf2f(wp[e]);
        }
        ushort_t pack[8];
#pragma unroll
        for (int e = 0; e < 8; ++e) pack[e] = f2bf(s[e]);
        *(float4*)&Wt[half][o * XLD + k * 64 + ic] = *(float4*)pack;
    }
    __syncthreads();

    const int lane = t8 & 63;
    const int l16 = lane & 15;
    const int quad = lane >> 4;
    const int bm = (t8 >> 6) * 16;  // wave's 16 b-rows (4 waves per half)

    f32x4 acc[4];
#pragma unroll
    for (int ji = 0; ji < 4; ++ji) acc[ji] = (f32x4){0.f, 0.f, 0.f, 0.f};

#pragma unroll
    for (int kc = 0; kc < 6; ++kc) {  // K = 192 = 6 x 32
        const short8 av = *(const short8*)&xg[half][(bm + l16) * XLD + kc * 32 + quad * 8];
#pragma unroll
        for (int ji = 0; ji < 4; ++ji) {
            const short8 bv = *(const short8*)&Wt[half][(ji * 16 + l16) * XLD + kc * 32 + quad * 8];
            acc[ji] = __builtin_amdgcn_mfma_f32_16x16x32_bf16(av, bv, acc[ji], 0, 0, 0);
        }
    }

    // C/D: col o = l16 + 16*ji, row b = bm + quad*4 + r.
#pragma unroll
    for (int ji = 0; ji < 4; ++ji) {
        const int o = ji * 16 + l16;
        const float bo = bias_s[half][o];
#pragma unroll
        for (int r = 0; r < 4; ++r) {
            const int b = bm + quad * 4 + r;
            out[((size_t)b * NN + n) * CC + o] = acc[ji][r] + bo;
        }
    }
}
#undef XLD

// ---------------------------------------------------------------------------
// Host launch: 4 dispatches.
// Workspace (bf16): Ab 8 | xT 16 (aliased by y2raw after gemm<0>) | xN 16 |
//   y1T 16 | y1N 16 | WpT 0.24  = 72.25 MB (was 88.25).
// ---------------------------------------------------------------------------
extern "C" void kernel_launch(void* const* d_in, const int* in_sizes, int n_in,
                              void* d_out, int out_size, void* d_ws, size_t ws_size,
                              hipStream_t stream) {
    const float* x  = (const float*)d_in[0];
    const float* E  = (const float*)d_in[1];
    const float* Wp = (const float*)d_in[2];
    const float* bp = (const float*)d_in[3];

    ushort_t* Ab  = (ushort_t*)d_ws;                    // [2048][2048]
    ushort_t* xT  = Ab + (size_t)NN * NN;               // [4096][2048]
    ushort_t* xN  = xT + (size_t)JJ * NN;               // [2048][4096]
    ushort_t* y1T = xN + (size_t)NN * JJ;               // [4096][2048]
    ushort_t* y1N = y1T + (size_t)JJ * NN;              // [2048][4096]
    ushort_t* WpT = y1N + (size_t)NN * JJ;              // [30][64][64]
    ushort_t* y2r = xT;                                 // alias: xT dead after gemm<0>
    float* out = (float*)d_out;

    prep_kernel<<<2 * NN + ED * KK, 256, 0, stream>>>(E, x, Wp, Ab, xT, xN, WpT);
    // y1 = A @ x : dual output (K-major + node-major)
    gemm_roll<0><<<256, 512, 0, stream>>>(Ab, xT, y1T, y1N);
    // y2raw = A @ y1 : node-major only (2*v - x folded into out_kernel)
    gemm_roll<1><<<256, 512, 0, stream>>>(Ab, y1T, nullptr, y2r);
    out_kernel<<<NN / 2, 512, 0, stream>>>(E, WpT, bp, xN, y1N, y2r, out);
}

// Round 11
// 200.068 us; speedup vs baseline: 1.0642x; 1.0642x over previous
//
#include <hip/hip_runtime.h>

// B=64, N=2048, DIM_IN=DIM_OUT=64, CHEB_K=3, EMBED_DIM=10
#define NN 2048
#define BB 64
#define CC 64
#define ED 10
#define KK 3
#define JJ (BB * CC)   // 4096

typedef unsigned short ushort_t;
typedef __attribute__((ext_vector_type(8))) short short8;   // 8 bf16 = 4 VGPRs
typedef __attribute__((ext_vector_type(4))) float f32x4;

typedef const __attribute__((address_space(1))) unsigned* gptr_t;
typedef __attribute__((address_space(3))) unsigned* lptr_t;
typedef __attribute__((address_space(3))) ushort_t* lsptr_t;
typedef const __attribute__((address_space(3))) short8* ls8_t;

static __device__ __forceinline__ ushort_t f2bf(float f) {
    union { float f; unsigned u; } x{f};
    unsigned r = x.u + 0x7FFF + ((x.u >> 16) & 1);  // RTN-even
    return (ushort_t)(r >> 16);
}
static __device__ __forceinline__ float bf2f(ushort_t h) {
    union { unsigned u; float f; } x;
    x.u = ((unsigned)h) << 16;
    return x.f;
}

// ---------------------------------------------------------------------------
// Kernel 1 (merged prep): round-7 version (float2 E-gather), verified.
// ---------------------------------------------------------------------------
__global__ __launch_bounds__(256) void prep_kernel(const float* __restrict__ E,
                                                   const float* __restrict__ x,
                                                   const float* __restrict__ Wp,
                                                   ushort_t* __restrict__ Ab,
                                                   ushort_t* __restrict__ xT,
                                                   ushort_t* __restrict__ xN,
                                                   ushort_t* __restrict__ WpT) {
    const int bid = blockIdx.x;
    const int tid = threadIdx.x;

    __shared__ float tb[64][68];
    __shared__ float red[8];

    if (bid < NN) {
        const int n = bid;
        float en[ED];
#pragma unroll
        for (int d = 0; d < ED; ++d) en[d] = E[n * ED + d];

        float sv[NN / 256];
        float lmax = 0.0f;
#pragma unroll
        for (int j = 0; j < NN / 256; ++j) {
            const int m = tid + j * 256;
            const float2* Em2 = (const float2*)(E + m * ED);  // 8-B aligned
            float dot = 0.0f;
#pragma unroll
            for (int d2 = 0; d2 < ED / 2; ++d2) {
                const float2 v = Em2[d2];
                dot += en[2 * d2] * v.x + en[2 * d2 + 1] * v.y;
            }
            float s = fmaxf(dot, 0.0f);
            sv[j] = s;
            lmax = fmaxf(lmax, s);
        }
#pragma unroll
        for (int off = 32; off > 0; off >>= 1) lmax = fmaxf(lmax, __shfl_down(lmax, off, 64));
        if ((tid & 63) == 0) red[tid >> 6] = lmax;
        __syncthreads();
        const float bmax = fmaxf(fmaxf(red[0], red[1]), fmaxf(red[2], red[3]));

        float lsum = 0.0f;
#pragma unroll
        for (int j = 0; j < NN / 256; ++j) {
            sv[j] = __expf(sv[j] - bmax);
            lsum += sv[j];
        }
#pragma unroll
        for (int off = 32; off > 0; off >>= 1) lsum += __shfl_down(lsum, off, 64);
        if ((tid & 63) == 0) red[4 + (tid >> 6)] = lsum;
        __syncthreads();
        const float inv = 1.0f / (red[4] + red[5] + red[6] + red[7]);

#pragma unroll
        for (int j = 0; j < NN / 256; ++j) {
            Ab[(size_t)n * NN + tid + j * 256] = f2bf(sv[j] * inv);
        }
    } else if (bid < 2 * NN) {
        const int t = bid - NN;
        const int n0 = (t & 31) * 64;
        const int b = t >> 5;

#pragma unroll
        for (int l = 0; l < 4; ++l) {
            const int idx = tid + l * 256;
            const int nn = idx >> 4;
            const int c4 = (idx & 15) << 2;
            const float4 v = *(const float4*)(x + ((size_t)b * NN + n0 + nn) * CC + c4);
            tb[c4 + 0][nn] = v.x;
            tb[c4 + 1][nn] = v.y;
            tb[c4 + 2][nn] = v.z;
            tb[c4 + 3][nn] = v.w;
        }
        __syncthreads();

#pragma unroll
        for (int l = 0; l < 2; ++l) {
            const int idx = tid + l * 256;
            const int c = idx >> 3;
            const int ch = (idx & 7) << 3;
            ushort_t pack[8];
#pragma unroll
            for (int e = 0; e < 8; ++e) pack[e] = f2bf(tb[c][ch + e]);
            *(float4*)(xT + (size_t)(b * 64 + c) * NN + n0 + ch) = *(float4*)pack;
        }
#pragma unroll
        for (int l = 0; l < 2; ++l) {
            const int idx = tid + l * 256;
            const int nn = idx >> 3;
            const int cg = (idx & 7) << 3;
            ushort_t pack[8];
#pragma unroll
            for (int e = 0; e < 8; ++e) pack[e] = f2bf(tb[cg + e][nn]);
            *(float4*)(xN + (size_t)(n0 + nn) * JJ + b * 64 + cg) = *(float4*)pack;
        }
    } else {
        const int dk = bid - 2 * NN;
        const float* src = Wp + (size_t)dk * CC * CC;

#pragma unroll
        for (int l = 0; l < 4; ++l) {
            const int idx = tid + l * 256;
            const int i = idx >> 4;
            const int o4 = (idx & 15) << 2;
            const float4 v = *(const float4*)(src + i * CC + o4);
            tb[o4 + 0][i] = v.x;
            tb[o4 + 1][i] = v.y;
            tb[o4 + 2][i] = v.z;
            tb[o4 + 3][i] = v.w;
        }
        __syncthreads();

#pragma unroll
        for (int l = 0; l < 2; ++l) {
            const int idx = tid + l * 256;
            const int o = idx >> 3;
            const int ic = (idx & 7) << 3;
            ushort_t pack[8];
#pragma unroll
            for (int e = 0; e < 8; ++e) pack[e] = f2bf(tb[o][ic + e]);
            *(float4*)(WpT + (size_t)dk * CC * CC + o * CC + ic) = *(float4*)pack;
        }
    }
}

// ---------------------------------------------------------------------------
// Kernel 2: rolled NT-GEMM — EXACT round-6 structure (best measured: 42.0 us).
// MODE 1 writes RAW acc (A@y1) node-major; the 2*v-x fold lives in out_kernel.
// ---------------------------------------------------------------------------
#define STAGE_A(bp, kt) do {                                                                \
    __builtin_amdgcn_global_load_lds(                                                       \
        (gptr_t)(srcA + (size_t)(kt) * 64),                                                 \
        (lptr_t)&(bp)[dstoff], 16, 0, 0);                                                   \
    __builtin_amdgcn_global_load_lds(                                                       \
        (gptr_t)(srcA + (size_t)64 * NN + (size_t)(kt) * 64),                               \
        (lptr_t)&(bp)[4096 + dstoff], 16, 0, 0);                                            \
} while (0)

#define STAGE_B(bp, h, kt) do {                                                             \
    __builtin_amdgcn_global_load_lds(                                                       \
        (gptr_t)(srcB + (size_t)((h) * 2) * 64 * NN + (size_t)(kt) * 64),                   \
        (lptr_t)&(bp)[8192 + (h) * 8192 + dstoff], 16, 0, 0);                               \
    __builtin_amdgcn_global_load_lds(                                                       \
        (gptr_t)(srcB + (size_t)((h) * 2 + 1) * 64 * NN + (size_t)(kt) * 64),               \
        (lptr_t)&(bp)[8192 + (h) * 8192 + 4096 + dstoff], 16, 0, 0);                        \
} while (0)

#define LDA_ALL(bp) do {                                                                    \
    _Pragma("unroll") for (int mi_ = 0; mi_ < 4; ++mi_)                                     \
    _Pragma("unroll") for (int ks_ = 0; ks_ < 2; ++ks_)                                     \
        a[mi_][ks_] = *(ls8_t)&(bp)[(aRG + mi_) * 1024 + ks_ * 512 + rdofs];                \
} while (0)

#define LDB_H(bp, h) do {                                                                   \
    _Pragma("unroll") for (int nn_ = 0; nn_ < 2; ++nn_)                                     \
    _Pragma("unroll") for (int ks_ = 0; ks_ < 2; ++ks_)                                     \
        b[(h) * 2 + nn_][ks_] =                                                             \
            *(ls8_t)&(bp)[8192 + (bRG + (h) * 2 + nn_) * 1024 + ks_ * 512 + rdofs];         \
} while (0)

// cluster c covers ni = 2c..2c+1: 4 mi x 2 ni x 2 ks = 16 MFMAs
#define MFMA_C(c) do {                                                                      \
    __builtin_amdgcn_s_setprio(1);                                                          \
    _Pragma("unroll") for (int mi_ = 0; mi_ < 4; ++mi_)                                     \
    _Pragma("unroll") for (int nn_ = 0; nn_ < 2; ++nn_) {                                   \
        acc[mi_][(c) * 2 + nn_] = __builtin_amdgcn_mfma_f32_16x16x32_bf16(                  \
            a[mi_][0], b[(c) * 2 + nn_][0], acc[mi_][(c) * 2 + nn_], 0, 0, 0);              \
        acc[mi_][(c) * 2 + nn_] = __builtin_amdgcn_mfma_f32_16x16x32_bf16(                  \
            a[mi_][1], b[(c) * 2 + nn_][1], acc[mi_][(c) * 2 + nn_], 0, 0, 0);              \
    }                                                                                       \
    __builtin_amdgcn_s_setprio(0);                                                          \
} while (0)

template <int MODE>
__global__ __launch_bounds__(512, 2) void gemm_roll(const ushort_t* __restrict__ A,
                                                    const ushort_t* __restrict__ Bt,
                                                    ushort_t* __restrict__ Ct,
                                                    ushort_t* __restrict__ Cn) {
    // bijective XCD swizzle (256 % 8 == 0)
    int bid = blockIdx.x;
    bid = (bid & 7) * 32 + (bid >> 3);
    const int bx = bid & 15;        // j-tile (BN=256)
    const int by = bid >> 4;        // m-tile (BM=128)
    const int j0 = bx * 256;
    const int m0 = by * 128;

    const int tid = threadIdx.x;
    const int w = tid >> 6;
    const int lane = tid & 63;
    const int l16 = lane & 15;
    const int quad = lane >> 4;
    const int wm = (w >> 2) * 64;   // wave rows [wm, wm+64)
    const int wn = (w & 3) * 64;    // wave cols [wn, wn+64)
    const int aRG = (w >> 2) * 4;   // A subtile base (8 subtiles of 16 rows)
    const int bRG = (w & 3) * 4;    // B subtile base (16 subtiles)
    // swizzled ds_read offset (ushorts): row l16, k-chunk quad, st_16x32 XOR
    const int rdofs = l16 * 32 + ((quad * 8) ^ ((l16 & 8) * 2));

    // staging: linear LDS dest (tid*16B); inverse-swizzled SOURCE
    const int r16s = lane >> 2;
    const int cx = (lane & 3) ^ ((r16s >> 3) << 1);
    const int rowbase = (w >> 1) * 16 + r16s;         // row within 64-row unit
    const int kofs = (w & 1) * 32 + cx * 8;
    const ushort_t* srcA = A + (size_t)(m0 + rowbase) * NN + kofs;
    const ushort_t* srcB = Bt + (size_t)(j0 + rowbase) * NN + kofs;
    const int dstoff = tid * 8;

    __shared__ ushort_t lds[3][24576];  // 3 x (A 16KB | B 32KB) = 144 KB

    lsptr_t p0 = (lsptr_t)&lds[0][0];   // buf(t)
    lsptr_t p1 = (lsptr_t)&lds[1][0];   // buf(t+1)
    lsptr_t p2 = (lsptr_t)&lds[2][0];   // buf(t+2) = stage target

    f32x4 acc[4][4];
#pragma unroll
    for (int mi = 0; mi < 4; ++mi)
#pragma unroll
        for (int ni = 0; ni < 4; ++ni) acc[mi][ni] = (f32x4){0.f, 0.f, 0.f, 0.f};

    short8 a[4][2], b[4][2];

    // Prologue: stage t0 (oldest) then t1. Loop-top vmcnt(6) drains t0.
    STAGE_A(p0, 0); STAGE_B(p0, 0, 0); STAGE_B(p0, 1, 0);
    STAGE_A(p1, 1); STAGE_B(p1, 0, 1); STAGE_B(p1, 1, 1);

#pragma unroll 1
    for (int t = 0; t < 32; ++t) {
        // deferred cluster of tile t-1 (old a, b[2..3]) covers drain + reads
        if (t) MFMA_C(1);
        if (t < 31) { asm volatile("s_waitcnt vmcnt(6)" ::: "memory"); }
        else        { asm volatile("s_waitcnt vmcnt(0)" ::: "memory"); }
        __builtin_amdgcn_sched_barrier(0);
        __builtin_amdgcn_s_barrier();          // buf(t) collectively landed

        LDA_ALL(p0); LDB_H(p0, 0);             // 12 ds_reads
        const bool stg = (t < 30);
        if (stg) { STAGE_A(p2, t + 2); STAGE_B(p2, 0, t + 2); }
        asm volatile("s_waitcnt lgkmcnt(0)" ::: "memory");
        __builtin_amdgcn_sched_barrier(0);
        MFMA_C(0);                              // 16 MFMAs cover:
        LDB_H(p0, 1);                           // 4 tail reads (b[2..3])
        if (stg) STAGE_B(p2, 1, t + 2);
        __builtin_amdgcn_sched_barrier(0);

        lsptr_t tp = p0; p0 = p1; p1 = p2; p2 = tp;  // rotate buffers
    }
    MFMA_C(1);  // tile 31's second cluster

    // Epilogue: C/D col j = l16, row m = quad*4 + r.
#pragma unroll
    for (int mi = 0; mi < 4; ++mi) {
#pragma unroll
        for (int ji = 0; ji < 4; ++ji) {
            const int j = j0 + wn + ji * 16 + l16;
            const int mb = m0 + wm + mi * 16 + quad * 4;
            ushort_t o[4];
#pragma unroll
            for (int r = 0; r < 4; ++r) o[r] = f2bf(acc[mi][ji][r]);
            if (MODE == 0) {
                *(unsigned long long*)(Ct + (size_t)j * NN + mb) = *(unsigned long long*)o;
            }
#pragma unroll
            for (int r = 0; r < 4; ++r) Cn[(size_t)(mb + r) * JJ + j] = o[r];
        }
    }
}

#undef STAGE_A
#undef STAGE_B
#undef LDA_ALL
#undef LDB_H
#undef MFMA_C

// ---------------------------------------------------------------------------
// Kernel 3: MFMA epilogue, round-11: NO xg staging. A-fragments load directly
// from global (each 16B chunk is consumed exactly once -> LDS staging was
// pure overhead, Common-mistake #7); the y2 fold (2*y2r - x) happens
// in-register on the k=2 fragments, reusing the xN fragments ax[0..1].
// E/bias via block-uniform s_loads + per-lane FMA (no LDS, no extra barrier).
// LDS = Wt only (25.6 KB) -> 6 blocks/CU (24 waves, was 4). One barrier.
// ---------------------------------------------------------------------------
#define XLD 200  // LDS row stride (bf16): 400 B
__global__ __launch_bounds__(256) void out_kernel(const float* __restrict__ E,
                                                  const ushort_t* __restrict__ WpT,
                                                  const float* __restrict__ bp,
                                                  const ushort_t* __restrict__ xN,
                                                  const ushort_t* __restrict__ y1N,
                                                  const ushort_t* __restrict__ y2r,
                                                  float* __restrict__ out) {
    const int n = blockIdx.x;
    const int tid = threadIdx.x;

    __shared__ ushort_t Wt[CC * XLD];  // 25.6 KB: Wt[o][k*64+i]

    float en[ED];
#pragma unroll
    for (int d = 0; d < ED; ++d) en[d] = E[n * ED + d];  // uniform -> s_load

    // synthesize Wt[o][ki] bf16: 1536 chunks of 8, fp32 accumulate over d
    for (int t = tid; t < CC * 24; t += 256) {
        const int o = t / 24;
        const int kc = t % 24;
        const int k = kc >> 3;
        const int ic = (kc & 7) << 3;
        float s[8];
#pragma unroll
        for (int e = 0; e < 8; ++e) s[e] = 0.0f;
#pragma unroll
        for (int d = 0; d < ED; ++d) {
            const float4 wv4 = *(const float4*)(WpT + ((size_t)(d * KK + k) * CC + o) * CC + ic);
            const ushort_t* wp = (const ushort_t*)&wv4;
#pragma unroll
            for (int e = 0; e < 8; ++e) s[e] += en[d] * bf2f(wp[e]);
        }
        ushort_t pack[8];
#pragma unroll
        for (int e = 0; e < 8; ++e) pack[e] = f2bf(s[e]);
        *(float4*)&Wt[o * XLD + k * 64 + ic] = *(float4*)pack;
    }
    __syncthreads();

    const int lane = tid & 63;
    const int l16 = lane & 15;
    const int quad = lane >> 4;
    const int bm = (tid >> 6) * 16;  // wave's 16 b-rows

    // per-lane bias for its 4 output columns o = ji*16 + l16
    float bo[4];
#pragma unroll
    for (int ji = 0; ji < 4; ++ji) {
        float s = 0.0f;
#pragma unroll
        for (int d = 0; d < ED; ++d) s += en[d] * bp[d * CC + ji * 16 + l16];
        bo[ji] = s;
    }

    f32x4 acc[4];
#pragma unroll
    for (int ji = 0; ji < 4; ++ji) acc[ji] = (f32x4){0.f, 0.f, 0.f, 0.f};

    const int rb = (bm + l16) * 64 + quad * 8;  // lane's row-base elem offset
    const ushort_t* xrow = xN + (size_t)n * JJ + rb;
    const ushort_t* y1row = y1N + (size_t)n * JJ + rb;
    const ushort_t* y2row = y2r + (size_t)n * JJ + rb;

    short8 ax[2];  // xN fragments (halves 0/1), reused by the k=2 fold

#pragma unroll
    for (int kc = 0; kc < 6; ++kc) {  // K = 192 = 6 x 32; k-stream = kc>>1
        const int h32 = (kc & 1) * 32;
        short8 av;
        if (kc < 2) {
            ax[kc] = *(const short8*)(xrow + h32);
            av = ax[kc];
        } else if (kc < 4) {
            av = *(const short8*)(y1row + h32);
        } else {
            const short8 v2 = *(const short8*)(y2row + h32);
            const ushort_t* p2 = (const ushort_t*)&v2;
            const ushort_t* px = (const ushort_t*)&ax[kc & 1];
            ushort_t pk[8];
#pragma unroll
            for (int e = 0; e < 8; ++e)
                pk[e] = f2bf(2.0f * bf2f(p2[e]) - bf2f(px[e]));
            av = *(short8*)pk;
        }
#pragma unroll
        for (int ji = 0; ji < 4; ++ji) {
            const short8 bv = *(const short8*)&Wt[(ji * 16 + l16) * XLD + kc * 32 + quad * 8];
            acc[ji] = __builtin_amdgcn_mfma_f32_16x16x32_bf16(av, bv, acc[ji], 0, 0, 0);
        }
    }

    // C/D: col o = l16 + 16*ji, row b = bm + quad*4 + r.
#pragma unroll
    for (int ji = 0; ji < 4; ++ji) {
        const int o = ji * 16 + l16;
#pragma unroll
        for (int r = 0; r < 4; ++r) {
            const int b = bm + quad * 4 + r;
            out[((size_t)b * NN + n) * CC + o] = acc[ji][r] + bo[ji];
        }
    }
}
#undef XLD

// ---------------------------------------------------------------------------
// Host launch: 4 dispatches.
// Workspace (bf16): Ab 8 | xT 16 (aliased by y2raw after gemm<0>) | xN 16 |
//   y1T 16 | y1N 16 | WpT 0.24  = 72.25 MB.
// ---------------------------------------------------------------------------
extern "C" void kernel_launch(void* const* d_in, const int* in_sizes, int n_in,
                              void* d_out, int out_size, void* d_ws, size_t ws_size,
                              hipStream_t stream) {
    const float* x  = (const float*)d_in[0];
    const float* E  = (const float*)d_in[1];
    const float* Wp = (const float*)d_in[2];
    const float* bp = (const float*)d_in[3];

    ushort_t* Ab  = (ushort_t*)d_ws;                    // [2048][2048]
    ushort_t* xT  = Ab + (size_t)NN * NN;               // [4096][2048]
    ushort_t* xN  = xT + (size_t)JJ * NN;               // [2048][4096]
    ushort_t* y1T = xN + (size_t)NN * JJ;               // [4096][2048]
    ushort_t* y1N = y1T + (size_t)JJ * NN;              // [2048][4096]
    ushort_t* WpT = y1N + (size_t)NN * JJ;              // [30][64][64]
    ushort_t* y2r = xT;                                 // alias: xT dead after gemm<0>
    float* out = (float*)d_out;

    prep_kernel<<<2 * NN + ED * KK, 256, 0, stream>>>(E, x, Wp, Ab, xT, xN, WpT);
    // y1 = A @ x : dual output (K-major + node-major)
    gemm_roll<0><<<256, 512, 0, stream>>>(Ab, xT, y1T, y1N);
    // y2raw = A @ y1 : node-major only (2*v - x folded into out_kernel)
    gemm_roll<1><<<256, 512, 0, stream>>>(Ab, y1T, nullptr, y2r);
    out_kernel<<<NN, 256, 0, stream>>>(E, WpT, bp, xN, y1N, y2r, out);
}